// Round 14
// baseline (219.331 us; speedup 1.0000x reference)
//
#include <hip/hip_runtime.h>
#include <math.h>

#define N_NODES 25000
#define N_EDGES 400000
#define E_TOT   (N_EDGES + N_NODES)
#define IN_CH   256
#define HID     128
#define HEADS   4
#define OUT_CH  64
#define HC1     512

static inline int cdiv(int a, int b) { return (a + b - 1) / b; }

typedef __attribute__((ext_vector_type(8))) short bf16x8;
typedef __attribute__((ext_vector_type(4))) float f32x4;

__device__ __forceinline__ unsigned short f2bf(float f) {
  union { float f; unsigned u; } v; v.f = f;
  unsigned r = v.u + 0x7fffu + ((v.u >> 16) & 1u);  // RNE
  return (unsigned short)(r >> 16);
}
__device__ __forceinline__ float bf2f(unsigned short b) {
  union { unsigned u; float f; } v; v.u = ((unsigned)b) << 16;
  return v.f;
}
__device__ __forceinline__ float lrelu(float v) { return v > 0.f ? v : 0.2f * v; }

__device__ __forceinline__ void glds16(const unsigned short* g, unsigned short* l) {
  __builtin_amdgcn_global_load_lds(
      (const __attribute__((address_space(1))) void*)g,
      (__attribute__((address_space(3))) void*)l, 16, 0, 0);
}

// ---- fused prep: edge-hist | x->bf16 | W1^T | W2^T | attn folds ----
#define B_HIST 1661   // cdiv(425000, 256)
#define B_CAST 6250   // 25000*256/4 / 256
#define B_WT1  512    // 256*512 / 256
#define B_WT2  128    // 512*64 / 256
#define B_F1   8      // 256*8 / 256
#define B_F2   4      // 512*2 / 256
__global__ __launch_bounds__(256) void prep_k(
    const int* __restrict__ dsts, int* __restrict__ cnt,
    const float* __restrict__ x, unsigned short* __restrict__ xb,
    const float* __restrict__ W1, unsigned short* __restrict__ Wt1,
    const float* __restrict__ W2, unsigned short* __restrict__ Wt2,
    const float* __restrict__ as1, const float* __restrict__ ad1, float* __restrict__ wb1,
    const float* __restrict__ as2, const float* __restrict__ ad2, float* __restrict__ wb2) {
  int b = blockIdx.x, t = threadIdx.x;
  if (b < B_HIST) {
    int e = b * 256 + t;
    if (e < E_TOT) {
      int d = (e < N_EDGES) ? dsts[e] : (e - N_EDGES);
      atomicAdd(&cnt[d], 1);
    }
  } else if (b < B_HIST + B_CAST) {
    int i = (b - B_HIST) * 256 + t;
    float4 v = *(const float4*)(x + (size_t)i * 4);
    ushort4 o;
    o.x = f2bf(v.x); o.y = f2bf(v.y); o.z = f2bf(v.z); o.w = f2bf(v.w);
    *(ushort4*)(xb + (size_t)i * 4) = o;
  } else if (b < B_HIST + B_CAST + B_WT1) {
    int i = (b - B_HIST - B_CAST) * 256 + t;   // i = n*K+k for Wt1[n][k]
    int n = i / IN_CH, k = i % IN_CH;
    Wt1[i] = f2bf(W1[(size_t)k * HC1 + n]);
  } else if (b < B_HIST + B_CAST + B_WT1 + B_WT2) {
    int i = (b - B_HIST - B_CAST - B_WT1) * 256 + t;
    int n = i / HC1, k = i % HC1;
    Wt2[i] = f2bf(W2[(size_t)k * OUT_CH + n]);
  } else if (b < B_HIST + B_CAST + B_WT1 + B_WT2 + B_F1) {
    int i = (b - B_HIST - B_CAST - B_WT1 - B_WT2) * 256 + t;  // K=256, O=8
    int k = i / 8, o = i % 8;
    int h = (o < 4) ? o : o - 4;
    const float* a = (o < 4) ? as1 : ad1;
    float acc = 0.f;
    for (int c = 0; c < HID; c++)
      acc += W1[(size_t)k * HC1 + h * HID + c] * a[h * HID + c];
    wb1[i] = acc;
  } else {
    int i = (b - B_HIST - B_CAST - B_WT1 - B_WT2 - B_F1) * 256 + t;  // K=512, O=2
    int k = i / 2, o = i % 2;
    const float* a = (o < 1) ? as2 : ad2;
    float acc = 0.f;
    for (int c = 0; c < OUT_CH; c++)
      acc += W2[(size_t)k * OUT_CH + c] * a[c];
    wb2[i] = acc;
  }
}

// ---- es/ed GEMV body: one wave per node ----
template <int K, int H, bool BF>
__device__ __forceinline__ void es_body(int nb, const void* __restrict__ in_,
                                        const float* __restrict__ wboth,
                                        float* __restrict__ es,
                                        float* __restrict__ ed) {
  const int O = 2 * H;
  const int KPL = K / 64;
  int lane = threadIdx.x & 63, wid = threadIdx.x >> 6;
  int n = nb * 4 + wid;
  if (n >= N_NODES) return;
  float wreg[KPL][O];
#pragma unroll
  for (int j = 0; j < KPL; j++)
#pragma unroll
    for (int o = 0; o < O; o++) wreg[j][o] = wboth[(size_t)(lane * KPL + j) * O + o];
  float p[O];
#pragma unroll
  for (int o = 0; o < O; o++) p[o] = 0.f;
  if (BF) {
    bf16x8 v8 = *(const bf16x8*)((const unsigned short*)in_ + (size_t)n * K + lane * KPL);
#pragma unroll
    for (int j = 0; j < KPL; j++) {
      float v = bf2f((unsigned short)v8[j]);
#pragma unroll
      for (int o = 0; o < O; o++) p[o] = fmaf(v, wreg[j][o], p[o]);
    }
  } else {
    float4 v4 = *(const float4*)((const float*)in_ + (size_t)n * K + lane * KPL);
    float vv[4] = {v4.x, v4.y, v4.z, v4.w};
#pragma unroll
    for (int j = 0; j < KPL; j++) {
#pragma unroll
      for (int o = 0; o < O; o++) p[o] = fmaf(vv[j], wreg[j][o], p[o]);
    }
  }
#pragma unroll
  for (int off = 32; off > 0; off >>= 1)
#pragma unroll
    for (int o = 0; o < O; o++) p[o] += __shfl_xor(p[o], off, 64);
  if (lane == 0) {
#pragma unroll
    for (int h = 0; h < H; h++) { es[n * H + h] = p[h]; ed[n * H + h] = p[H + h]; }
  }
}

// ---- MFMA GEMM body, m97 structure: BM=128, BK=32, global_load_lds ----
template <int BN>
__device__ __forceinline__ void gemm_body(
    unsigned short* __restrict__ As, unsigned short* __restrict__ Bs,
    const unsigned short* __restrict__ A, const unsigned short* __restrict__ Bt,
    unsigned short* __restrict__ C, int M, int N, int K, int bx, int by) {
  const int BM = 128, BK = 32;
  const int NB = BN / 32;
  int tid = threadIdx.x;
  int w = tid >> 6, l = tid & 63;
  int wr = w >> 1, wc = w & 1;
  int row0 = by * BM, col0 = bx * BN;
  int lr = l & 15, kg = l >> 4;
  int lrow = l >> 2, lk = (l & 3) * 8;

  f32x4 acc[4][NB] = {};

  int ar0 = min(row0 + w * 16 + lrow, M - 1);
  int ar1 = min(row0 + 64 + w * 16 + lrow, M - 1);
  const unsigned short* Ap0 = A + (size_t)ar0 * K + lk;
  const unsigned short* Ap1 = A + (size_t)ar1 * K + lk;
  unsigned short* AsW0 = As + (w * 16) * BK;
  unsigned short* AsW1 = As + (64 + w * 16) * BK;
  const unsigned short* Bp0 = Bt + (size_t)(col0 + w * 16 + lrow) * K + lk;
  unsigned short* BsW0 = Bs + (w * 16) * BK;
  int bcol1 = (BN == 128) ? (col0 + 64 + w * 16 + lrow) : 0;
  const unsigned short* Bp1 = Bt + (size_t)bcol1 * K + lk;
  unsigned short* BsW1 = Bs + ((BN == 128 ? 64 + w * 16 : 0)) * BK;

  for (int k0 = 0; k0 < K; k0 += BK) {
    glds16(Ap0 + k0, AsW0);
    glds16(Ap1 + k0, AsW1);
    glds16(Bp0 + k0, BsW0);
    if (BN == 128) glds16(Bp1 + k0, BsW1);
    __syncthreads();
    bf16x8 af[4], bfr[NB];
#pragma unroll
    for (int m = 0; m < 4; m++)
      af[m] = *(const bf16x8*)&As[(wr * 64 + m * 16 + lr) * BK + kg * 8];
#pragma unroll
    for (int n = 0; n < NB; n++)
      bfr[n] = *(const bf16x8*)&Bs[(wc * (BN / 2) + n * 16 + lr) * BK + kg * 8];
#pragma unroll
    for (int m = 0; m < 4; m++)
#pragma unroll
      for (int n = 0; n < NB; n++)
        acc[m][n] = __builtin_amdgcn_mfma_f32_16x16x32_bf16(af[m], bfr[n], acc[m][n], 0, 0, 0);
    __syncthreads();
  }
#pragma unroll
  for (int m = 0; m < 4; m++) {
#pragma unroll
    for (int n = 0; n < NB; n++) {
      int col = col0 + wc * (BN / 2) + n * 16 + lr;
#pragma unroll
      for (int r = 0; r < 4; r++) {
        int row = row0 + wr * 64 + m * 16 + kg * 4 + r;
        if (row < M) C[(size_t)row * N + col] = f2bf(acc[m][n][r]);
      }
    }
  }
}

// ================= CSR scan =================
#define SCAN_T 1024
#define SCAN_C 25
__global__ __launch_bounds__(SCAN_T) void scan_k(const int* __restrict__ cnt,
                                                 int* __restrict__ rs,
                                                 int* __restrict__ cursor) {
  __shared__ int part[16];
  int t = threadIdx.x, lane = t & 63, wid = t >> 6;
  int base = t * SCAN_C;
  int loc[SCAN_C];
  int sum = 0;
#pragma unroll
  for (int i = 0; i < SCAN_C; i++) {
    int idx = base + i;
    int v = (idx < N_NODES) ? cnt[idx] : 0;
    loc[i] = sum;
    sum += v;
  }
  int incl = sum;
#pragma unroll
  for (int off = 1; off < 64; off <<= 1) {
    int u = __shfl_up(incl, off, 64);
    if (lane >= off) incl += u;
  }
  if (lane == 63) part[wid] = incl;
  __syncthreads();
  if (t == 0) {
    int run = 0;
#pragma unroll
    for (int wv = 0; wv < 16; wv++) { int v = part[wv]; part[wv] = run; run += v; }
  }
  __syncthreads();
  int off0 = part[wid] + incl - sum;
#pragma unroll
  for (int i = 0; i < SCAN_C; i++) {
    int idx = base + i;
    if (idx < N_NODES) {
      rs[idx] = off0 + loc[i];
      cursor[idx] = 0;
    }
  }
  if (t == 0) rs[N_NODES] = E_TOT;
}

// ===== merged phase C: gemm1 | CSR fill | layer-1 es/ed GEMV =====
#define G1_BLK 784   // 4 col-blocks x 196 row-blocks
#define GE_BLK 1661
__global__ __launch_bounds__(256) void gemm1_fill_es1_k(
    const unsigned short* __restrict__ xb, const unsigned short* __restrict__ Wt1,
    unsigned short* __restrict__ h1b,
    const int* __restrict__ src, const int* __restrict__ dst,
    const int* __restrict__ rs, int* __restrict__ cursor,
    int* __restrict__ csr_src,
    const float* __restrict__ wb1,
    float* __restrict__ es1, float* __restrict__ ed1) {
  __shared__ __attribute__((aligned(16))) unsigned short As[128 * 32];
  __shared__ __attribute__((aligned(16))) unsigned short Bs[128 * 32];
  int b = blockIdx.x;
  if (b < G1_BLK) {
    gemm_body<128>(As, Bs, xb, Wt1, h1b, N_NODES, HC1, IN_CH, b & 3, b >> 2);
  } else if (b < G1_BLK + GE_BLK) {
    int e = (b - G1_BLK) * 256 + threadIdx.x;
    if (e >= E_TOT) return;
    int s, d;
    if (e < N_EDGES) { s = src[e]; d = dst[e]; } else { s = d = e - N_EDGES; }
    int pos = atomicAdd(&cursor[d], 1);
    csr_src[rs[d] + pos] = s;
  } else {
    es_body<IN_CH, HEADS, true>(b - G1_BLK - GE_BLK, xb, wb1, es1, ed1);
  }
}

// ===== layer-1 alpha + denom: one wave per node =====
__global__ __launch_bounds__(256) void alpha_k(
    const float* __restrict__ es, const float* __restrict__ ed,
    const int* __restrict__ rs, const int* __restrict__ csr,
    float* __restrict__ alphaH, float4* __restrict__ inv4) {
  int lane = threadIdx.x & 63, wid = threadIdx.x >> 6;
  int n = blockIdx.x * 4 + wid;
  if (n >= N_NODES) return;
  int beg = rs[n], deg = rs[n + 1] - beg;
  float4 edn = *(const float4*)(ed + n * 4);
  float s0 = 0.f, s1 = 0.f, s2 = 0.f, s3 = 0.f;
  for (int i = lane; i < deg; i += 64) {
    int e = beg + i;
    int s = csr[e];
    float4 ev = *(const float4*)(es + s * 4);
    float p0 = __expf(lrelu(ev.x + edn.x));
    float p1 = __expf(lrelu(ev.y + edn.y));
    float p2 = __expf(lrelu(ev.z + edn.z));
    float p3 = __expf(lrelu(ev.w + edn.w));
    alphaH[e] = p0;
    alphaH[E_TOT + e] = p1;
    alphaH[2 * E_TOT + e] = p2;
    alphaH[3 * E_TOT + e] = p3;
    s0 += p0; s1 += p1; s2 += p2; s3 += p3;
  }
#pragma unroll
  for (int off = 32; off > 0; off >>= 1) {
    s0 += __shfl_xor(s0, off, 64);
    s1 += __shfl_xor(s1, off, 64);
    s2 += __shfl_xor(s2, off, 64);
    s3 += __shfl_xor(s3, off, 64);
  }
  if (lane == 0) {
    float4 r;
    r.x = 1.f / (s0 + 1e-16f);
    r.y = 1.f / (s1 + 1e-16f);
    r.z = 1.f / (s2 + 1e-16f);
    r.w = 1.f / (s3 + 1e-16f);
    inv4[n] = r;
  }
}

// ===== merged: layer-2 GEMM (25000x64x512) | layer-2 es/ed GEMV =====
#define G2_BLK 196
__global__ __launch_bounds__(256) void gemm2_es2_k(
    const unsigned short* __restrict__ out1b, const unsigned short* __restrict__ Wt2,
    unsigned short* __restrict__ h2b,
    const float* __restrict__ wb2, float* __restrict__ es2, float* __restrict__ ed2) {
  __shared__ __attribute__((aligned(16))) unsigned short As[128 * 32];
  __shared__ __attribute__((aligned(16))) unsigned short Bs[64 * 32];
  int b = blockIdx.x;
  if (b < G2_BLK) {
    gemm_body<64>(As, Bs, out1b, Wt2, h2b, N_NODES, OUT_CH, HC1, 0, b);
  } else {
    es_body<HC1, 1, true>(b - G2_BLK, out1b, wb2, es2, ed2);
  }
}

// ===== layer-1 gather: channel-sliced + group-per-node + shfl-distribute MLP-8 =====
// Feature loads use UNIFORM base + 32-bit voffset (saddr form): off = (s<<9)+c0
// in shorts (max 12.8M, fits 32-bit) -> ~1 VALU of addr math per load vs 4-5
// for the per-lane 64-bit base form.
__global__ __launch_bounds__(256) void gat_agg1_g8(
    const unsigned short* __restrict__ hfeat,
    const float* __restrict__ alphaH,
    const int* __restrict__ rs, const int* __restrict__ csr,
    const float4* __restrict__ inv4, const float* __restrict__ bias,
    unsigned short* __restrict__ out) {
  int b = blockIdx.x;
  int g = b & 7;                        // channel slice 0..7
  int lane = threadIdx.x & 63, wid = threadIdx.x >> 6;
  int grp = lane >> 3, cl = lane & 7;
  int n = (b >> 3) * 32 + wid * 8 + grp;
  bool valid = n < N_NODES;
  int nn = valid ? n : N_NODES - 1;
  int h = g >> 1;
  unsigned c0 = (unsigned)(g * 64 + cl * 8);
  int beg = rs[nn], end = rs[nn + 1];
  const float* aH = alphaH + (size_t)h * E_TOT;
  int gbase = grp * 8;

  float acc[8] = {};
  for (int i = beg; i < end; i += 8) {
    int idx = i + cl;
    bool inb = idx < end;
    int sv = csr[inb ? idx : end - 1];
    float av = inb ? aH[idx] : 0.f;
#pragma unroll
    for (int e = 0; e < 8; e++) {
      unsigned s = (unsigned)__shfl(sv, gbase + e, 64);
      float p = __shfl(av, gbase + e, 64);
      bf16x8 hv = *(const bf16x8*)(hfeat + ((s << 9) + c0));
#pragma unroll
      for (int j = 0; j < 8; j++) acc[j] = fmaf(bf2f((unsigned short)hv[j]), p, acc[j]);
    }
  }
  if (valid) {
    float inv = ((const float*)&inv4[nn])[h];
    bf16x8 o;
#pragma unroll
    for (int j = 0; j < 8; j++) {
      float v = acc[j] * inv + bias[c0 + j];
      v = v > 0.f ? v : expm1f(v);  // ELU
      o[j] = (short)f2bf(v);
    }
    *(bf16x8*)(out + (size_t)n * 512 + c0) = o;
  }
}

// ===== layer-2 gather: group-per-node, inline softmax, saddr addressing =====
__global__ __launch_bounds__(256) void gat_agg2_g8(
    const unsigned short* __restrict__ hfeat,
    const float* __restrict__ es, const float* __restrict__ ed,
    const int* __restrict__ rs, const int* __restrict__ csr,
    const float* __restrict__ bias, float* __restrict__ out) {
  int lane = threadIdx.x & 63, wid = threadIdx.x >> 6;
  int grp = lane >> 3, cl = lane & 7;
  int n = blockIdx.x * 32 + wid * 8 + grp;
  bool valid = n < N_NODES;
  int nn = valid ? n : N_NODES - 1;
  unsigned c0 = (unsigned)(cl * 8);
  int beg = rs[nn], end = rs[nn + 1];
  int gbase = grp * 8;
  float edn = ed[nn];

  // pass 1: denominator
  float sum = 0.f;
  for (int i = beg + cl; i < end; i += 8) {
    int s = csr[i];
    sum += __expf(lrelu(es[s] + edn));
  }
#pragma unroll
  for (int off = 1; off < 8; off <<= 1) sum += __shfl_xor(sum, off, 64);
  float inv = 1.f / (sum + 1e-16f);

  // pass 2: gather with inline p
  float acc[8] = {};
  for (int i = beg; i < end; i += 8) {
    int idx = i + cl;
    bool inb = idx < end;
    int sv = csr[inb ? idx : end - 1];
    float av = inb ? __expf(lrelu(es[sv] + edn)) : 0.f;
#pragma unroll
    for (int e = 0; e < 8; e++) {
      unsigned s = (unsigned)__shfl(sv, gbase + e, 64);
      float p = __shfl(av, gbase + e, 64);
      bf16x8 hv = *(const bf16x8*)(hfeat + ((s << 6) + c0));
#pragma unroll
      for (int j = 0; j < 8; j++) acc[j] = fmaf(bf2f((unsigned short)hv[j]), p, acc[j]);
    }
  }
  if (valid) {
    float4 o0, o1;
    o0.x = acc[0] * inv + bias[c0];
    o0.y = acc[1] * inv + bias[c0 + 1];
    o0.z = acc[2] * inv + bias[c0 + 2];
    o0.w = acc[3] * inv + bias[c0 + 3];
    o1.x = acc[4] * inv + bias[c0 + 4];
    o1.y = acc[5] * inv + bias[c0 + 5];
    o1.z = acc[6] * inv + bias[c0 + 6];
    o1.w = acc[7] * inv + bias[c0 + 7];
    *(float4*)(out + (size_t)n * 64 + c0) = o0;
    *(float4*)(out + (size_t)n * 64 + c0 + 4) = o1;
  }
}

extern "C" void kernel_launch(void* const* d_in, const int* in_sizes, int n_in,
                              void* d_out, int out_size, void* d_ws, size_t ws_size,
                              hipStream_t stream) {
  const float* x   = (const float*)d_in[0];
  const int*   ei  = (const int*)d_in[1];
  const float* W1  = (const float*)d_in[2];
  const float* as1 = (const float*)d_in[3];
  const float* ad1 = (const float*)d_in[4];
  const float* b1  = (const float*)d_in[5];
  const float* W2  = (const float*)d_in[6];
  const float* as2 = (const float*)d_in[7];
  const float* ad2 = (const float*)d_in[8];
  const float* b2  = (const float*)d_in[9];
  float* out = (float*)d_out;

  const int* srcs = ei;
  const int* dsts = ei + N_EDGES;

  char* ws = (char*)d_ws;
  auto alloc = [&](size_t bytes) -> char* {
    char* p = ws;
    ws += (bytes + 255) & ~(size_t)255;
    return p;
  };
  unsigned short* xb    = (unsigned short*)alloc((size_t)N_NODES * IN_CH * 2);
  unsigned short* Wt1   = (unsigned short*)alloc((size_t)IN_CH * HC1 * 2);
  unsigned short* Wt2   = (unsigned short*)alloc((size_t)HC1 * OUT_CH * 2);
  unsigned short* h1b   = (unsigned short*)alloc((size_t)N_NODES * HC1 * 2);
  unsigned short* out1b = (unsigned short*)alloc((size_t)N_NODES * HC1 * 2);
  unsigned short* h2b   = (unsigned short*)alloc((size_t)N_NODES * OUT_CH * 2);
  float* wb1    = (float*)alloc((size_t)IN_CH * 2 * HEADS * 4);
  float* wb2    = (float*)alloc((size_t)HC1 * 2 * 4);
  float* es1    = (float*)alloc((size_t)N_NODES * HEADS * 4);
  float* ed1    = (float*)alloc((size_t)N_NODES * HEADS * 4);
  float* es2    = (float*)alloc((size_t)N_NODES * 4);
  float* ed2    = (float*)alloc((size_t)N_NODES * 4);
  float* inv4   = (float*)alloc((size_t)N_NODES * 4 * 4);
  float* alphaH = (float*)alloc((size_t)4 * E_TOT * 4);
  int*   cnt    = (int*)alloc((size_t)N_NODES * 4);
  int*   rs     = (int*)alloc((size_t)(N_NODES + 1) * 4);
  int*   cursor = (int*)alloc((size_t)N_NODES * 4);
  int*   csrS   = (int*)alloc((size_t)E_TOT * 4);

  hipMemsetAsync(cnt, 0, (size_t)N_NODES * 4, stream);

  const int gn4 = cdiv(N_NODES, 4);    // 6250
  const int gn32 = cdiv(N_NODES, 32);  // 782

  // phase A: hist + casts + transposes + folds
  prep_k<<<B_HIST + B_CAST + B_WT1 + B_WT2 + B_F1 + B_F2, 256, 0, stream>>>(
      dsts, cnt, x, xb, W1, Wt1, W2, Wt2, as1, ad1, wb1, as2, ad2, wb2);
  // phase B: scan
  scan_k<<<1, SCAN_T, 0, stream>>>(cnt, rs, cursor);
  // phase C: gemm1 | CSR fill | es1/ed1 GEMV
  gemm1_fill_es1_k<<<G1_BLK + GE_BLK + gn4, 256, 0, stream>>>(
      xb, Wt1, h1b, srcs, dsts, rs, cursor, csrS, wb1, es1, ed1);
  // phase D: alpha+denom
  alpha_k<<<gn4, 256, 0, stream>>>(es1, ed1, rs, csrS, alphaH, (float4*)inv4);
  // phase E: layer-1 aggregate
  gat_agg1_g8<<<gn32 * 8, 256, 0, stream>>>(
      h1b, alphaH, rs, csrS, (const float4*)inv4, b1, out1b);
  // phase F: gemm2 | es2/ed2 GEMV
  gemm2_es2_k<<<G2_BLK + gn4, 256, 0, stream>>>(
      out1b, Wt2, h2b, wb2, es2, ed2);
  // phase G: layer-2 aggregate (inline softmax)
  gat_agg2_g8<<<gn32, 256, 0, stream>>>(h2b, es2, ed2, rs, csrS, b2, out);
}

// Round 15
// 218.146 us; speedup vs baseline: 1.0054x; 1.0054x over previous
//
#include <hip/hip_runtime.h>
#include <math.h>

#define N_NODES 25000
#define N_EDGES 400000
#define E_TOT   (N_EDGES + N_NODES)
#define IN_CH   256
#define HID     128
#define HEADS   4
#define OUT_CH  64
#define HC1     512

static inline int cdiv(int a, int b) { return (a + b - 1) / b; }

typedef __attribute__((ext_vector_type(8))) short bf16x8;
typedef __attribute__((ext_vector_type(4))) float f32x4;

__device__ __forceinline__ unsigned short f2bf(float f) {
  union { float f; unsigned u; } v; v.f = f;
  unsigned r = v.u + 0x7fffu + ((v.u >> 16) & 1u);  // RNE
  return (unsigned short)(r >> 16);
}
__device__ __forceinline__ float bf2f(unsigned short b) {
  union { unsigned u; float f; } v; v.u = ((unsigned)b) << 16;
  return v.f;
}
__device__ __forceinline__ float lrelu(float v) { return v > 0.f ? v : 0.2f * v; }

__device__ __forceinline__ void glds16(const unsigned short* g, unsigned short* l) {
  __builtin_amdgcn_global_load_lds(
      (const __attribute__((address_space(1))) void*)g,
      (__attribute__((address_space(3))) void*)l, 16, 0, 0);
}

// ---- fused prep: edge-hist | x->bf16 | W1^T | W2^T | attn folds ----
#define B_HIST 1661   // cdiv(425000, 256)
#define B_CAST 6250   // 25000*256/4 / 256
#define B_WT1  512    // 256*512 / 256
#define B_WT2  128    // 512*64 / 256
#define B_F1   8      // 256*8 / 256
#define B_F2   4      // 512*2 / 256
__global__ __launch_bounds__(256) void prep_k(
    const int* __restrict__ dsts, int* __restrict__ cnt,
    const float* __restrict__ x, unsigned short* __restrict__ xb,
    const float* __restrict__ W1, unsigned short* __restrict__ Wt1,
    const float* __restrict__ W2, unsigned short* __restrict__ Wt2,
    const float* __restrict__ as1, const float* __restrict__ ad1, float* __restrict__ wb1,
    const float* __restrict__ as2, const float* __restrict__ ad2, float* __restrict__ wb2) {
  int b = blockIdx.x, t = threadIdx.x;
  if (b < B_HIST) {
    int e = b * 256 + t;
    if (e < E_TOT) {
      int d = (e < N_EDGES) ? dsts[e] : (e - N_EDGES);
      atomicAdd(&cnt[d], 1);
    }
  } else if (b < B_HIST + B_CAST) {
    int i = (b - B_HIST) * 256 + t;
    float4 v = *(const float4*)(x + (size_t)i * 4);
    ushort4 o;
    o.x = f2bf(v.x); o.y = f2bf(v.y); o.z = f2bf(v.z); o.w = f2bf(v.w);
    *(ushort4*)(xb + (size_t)i * 4) = o;
  } else if (b < B_HIST + B_CAST + B_WT1) {
    int i = (b - B_HIST - B_CAST) * 256 + t;   // i = n*K+k for Wt1[n][k]
    int n = i / IN_CH, k = i % IN_CH;
    Wt1[i] = f2bf(W1[(size_t)k * HC1 + n]);
  } else if (b < B_HIST + B_CAST + B_WT1 + B_WT2) {
    int i = (b - B_HIST - B_CAST - B_WT1) * 256 + t;
    int n = i / HC1, k = i % HC1;
    Wt2[i] = f2bf(W2[(size_t)k * OUT_CH + n]);
  } else if (b < B_HIST + B_CAST + B_WT1 + B_WT2 + B_F1) {
    int i = (b - B_HIST - B_CAST - B_WT1 - B_WT2) * 256 + t;  // K=256, O=8
    int k = i / 8, o = i % 8;
    int h = (o < 4) ? o : o - 4;
    const float* a = (o < 4) ? as1 : ad1;
    float acc = 0.f;
    for (int c = 0; c < HID; c++)
      acc += W1[(size_t)k * HC1 + h * HID + c] * a[h * HID + c];
    wb1[i] = acc;
  } else {
    int i = (b - B_HIST - B_CAST - B_WT1 - B_WT2 - B_F1) * 256 + t;  // K=512, O=2
    int k = i / 2, o = i % 2;
    const float* a = (o < 1) ? as2 : ad2;
    float acc = 0.f;
    for (int c = 0; c < OUT_CH; c++)
      acc += W2[(size_t)k * OUT_CH + c] * a[c];
    wb2[i] = acc;
  }
}

// ---- es/ed GEMV body: one wave per node ----
template <int K, int H, bool BF>
__device__ __forceinline__ void es_body(int nb, const void* __restrict__ in_,
                                        const float* __restrict__ wboth,
                                        float* __restrict__ es,
                                        float* __restrict__ ed) {
  const int O = 2 * H;
  const int KPL = K / 64;
  int lane = threadIdx.x & 63, wid = threadIdx.x >> 6;
  int n = nb * 4 + wid;
  if (n >= N_NODES) return;
  float wreg[KPL][O];
#pragma unroll
  for (int j = 0; j < KPL; j++)
#pragma unroll
    for (int o = 0; o < O; o++) wreg[j][o] = wboth[(size_t)(lane * KPL + j) * O + o];
  float p[O];
#pragma unroll
  for (int o = 0; o < O; o++) p[o] = 0.f;
  if (BF) {
    bf16x8 v8 = *(const bf16x8*)((const unsigned short*)in_ + (size_t)n * K + lane * KPL);
#pragma unroll
    for (int j = 0; j < KPL; j++) {
      float v = bf2f((unsigned short)v8[j]);
#pragma unroll
      for (int o = 0; o < O; o++) p[o] = fmaf(v, wreg[j][o], p[o]);
    }
  } else {
    float4 v4 = *(const float4*)((const float*)in_ + (size_t)n * K + lane * KPL);
    float vv[4] = {v4.x, v4.y, v4.z, v4.w};
#pragma unroll
    for (int j = 0; j < KPL; j++) {
#pragma unroll
      for (int o = 0; o < O; o++) p[o] = fmaf(vv[j], wreg[j][o], p[o]);
    }
  }
#pragma unroll
  for (int off = 32; off > 0; off >>= 1)
#pragma unroll
    for (int o = 0; o < O; o++) p[o] += __shfl_xor(p[o], off, 64);
  if (lane == 0) {
#pragma unroll
    for (int h = 0; h < H; h++) { es[n * H + h] = p[h]; ed[n * H + h] = p[H + h]; }
  }
}

// ---- MFMA GEMM body, m97 structure: BM=128, BK=32, global_load_lds ----
template <int BN>
__device__ __forceinline__ void gemm_body(
    unsigned short* __restrict__ As, unsigned short* __restrict__ Bs,
    const unsigned short* __restrict__ A, const unsigned short* __restrict__ Bt,
    unsigned short* __restrict__ C, int M, int N, int K, int bx, int by) {
  const int BM = 128, BK = 32;
  const int NB = BN / 32;
  int tid = threadIdx.x;
  int w = tid >> 6, l = tid & 63;
  int wr = w >> 1, wc = w & 1;
  int row0 = by * BM, col0 = bx * BN;
  int lr = l & 15, kg = l >> 4;
  int lrow = l >> 2, lk = (l & 3) * 8;

  f32x4 acc[4][NB] = {};

  int ar0 = min(row0 + w * 16 + lrow, M - 1);
  int ar1 = min(row0 + 64 + w * 16 + lrow, M - 1);
  const unsigned short* Ap0 = A + (size_t)ar0 * K + lk;
  const unsigned short* Ap1 = A + (size_t)ar1 * K + lk;
  unsigned short* AsW0 = As + (w * 16) * BK;
  unsigned short* AsW1 = As + (64 + w * 16) * BK;
  const unsigned short* Bp0 = Bt + (size_t)(col0 + w * 16 + lrow) * K + lk;
  unsigned short* BsW0 = Bs + (w * 16) * BK;
  int bcol1 = (BN == 128) ? (col0 + 64 + w * 16 + lrow) : 0;
  const unsigned short* Bp1 = Bt + (size_t)bcol1 * K + lk;
  unsigned short* BsW1 = Bs + ((BN == 128 ? 64 + w * 16 : 0)) * BK;

  for (int k0 = 0; k0 < K; k0 += BK) {
    glds16(Ap0 + k0, AsW0);
    glds16(Ap1 + k0, AsW1);
    glds16(Bp0 + k0, BsW0);
    if (BN == 128) glds16(Bp1 + k0, BsW1);
    __syncthreads();
    bf16x8 af[4], bfr[NB];
#pragma unroll
    for (int m = 0; m < 4; m++)
      af[m] = *(const bf16x8*)&As[(wr * 64 + m * 16 + lr) * BK + kg * 8];
#pragma unroll
    for (int n = 0; n < NB; n++)
      bfr[n] = *(const bf16x8*)&Bs[(wc * (BN / 2) + n * 16 + lr) * BK + kg * 8];
#pragma unroll
    for (int m = 0; m < 4; m++)
#pragma unroll
      for (int n = 0; n < NB; n++)
        acc[m][n] = __builtin_amdgcn_mfma_f32_16x16x32_bf16(af[m], bfr[n], acc[m][n], 0, 0, 0);
    __syncthreads();
  }
#pragma unroll
  for (int m = 0; m < 4; m++) {
#pragma unroll
    for (int n = 0; n < NB; n++) {
      int col = col0 + wc * (BN / 2) + n * 16 + lr;
#pragma unroll
      for (int r = 0; r < 4; r++) {
        int row = row0 + wr * 64 + m * 16 + kg * 4 + r;
        if (row < M) C[(size_t)row * N + col] = f2bf(acc[m][n][r]);
      }
    }
  }
}

// ================= CSR scan =================
#define SCAN_T 1024
#define SCAN_C 25
__global__ __launch_bounds__(SCAN_T) void scan_k(const int* __restrict__ cnt,
                                                 int* __restrict__ rs,
                                                 int* __restrict__ cursor) {
  __shared__ int part[16];
  int t = threadIdx.x, lane = t & 63, wid = t >> 6;
  int base = t * SCAN_C;
  int loc[SCAN_C];
  int sum = 0;
#pragma unroll
  for (int i = 0; i < SCAN_C; i++) {
    int idx = base + i;
    int v = (idx < N_NODES) ? cnt[idx] : 0;
    loc[i] = sum;
    sum += v;
  }
  int incl = sum;
#pragma unroll
  for (int off = 1; off < 64; off <<= 1) {
    int u = __shfl_up(incl, off, 64);
    if (lane >= off) incl += u;
  }
  if (lane == 63) part[wid] = incl;
  __syncthreads();
  if (t == 0) {
    int run = 0;
#pragma unroll
    for (int wv = 0; wv < 16; wv++) { int v = part[wv]; part[wv] = run; run += v; }
  }
  __syncthreads();
  int off0 = part[wid] + incl - sum;
#pragma unroll
  for (int i = 0; i < SCAN_C; i++) {
    int idx = base + i;
    if (idx < N_NODES) {
      rs[idx] = off0 + loc[i];
      cursor[idx] = 0;
    }
  }
  if (t == 0) rs[N_NODES] = E_TOT;
}

// ===== merged: CSR fill | layer-1 es/ed GEMV =====
#define GE_BLK 1661
__global__ __launch_bounds__(256) void fill_es1_k(
    const int* __restrict__ src, const int* __restrict__ dst,
    const int* __restrict__ rs, int* __restrict__ cursor,
    int* __restrict__ csr_src,
    const unsigned short* __restrict__ xb, const float* __restrict__ wb1,
    float* __restrict__ es1, float* __restrict__ ed1) {
  int b = blockIdx.x;
  if (b < GE_BLK) {
    int e = b * 256 + threadIdx.x;
    if (e >= E_TOT) return;
    int s, d;
    if (e < N_EDGES) { s = src[e]; d = dst[e]; } else { s = d = e - N_EDGES; }
    int pos = atomicAdd(&cursor[d], 1);
    csr_src[rs[d] + pos] = s;
  } else {
    es_body<IN_CH, HEADS, true>(b - GE_BLK, xb, wb1, es1, ed1);
  }
}

// ---- layer-1 alpha body: one wave per node ----
__device__ __forceinline__ void alpha_body(
    int nb, const float* __restrict__ es, const float* __restrict__ ed,
    const int* __restrict__ rs, const int* __restrict__ csr,
    float* __restrict__ alphaH, float4* __restrict__ inv4) {
  int lane = threadIdx.x & 63, wid = threadIdx.x >> 6;
  int n = nb * 4 + wid;
  if (n >= N_NODES) return;
  int beg = rs[n], deg = rs[n + 1] - beg;
  float4 edn = *(const float4*)(ed + n * 4);
  float s0 = 0.f, s1 = 0.f, s2 = 0.f, s3 = 0.f;
  for (int i = lane; i < deg; i += 64) {
    int e = beg + i;
    int s = csr[e];
    float4 ev = *(const float4*)(es + s * 4);
    float p0 = __expf(lrelu(ev.x + edn.x));
    float p1 = __expf(lrelu(ev.y + edn.y));
    float p2 = __expf(lrelu(ev.z + edn.z));
    float p3 = __expf(lrelu(ev.w + edn.w));
    alphaH[e] = p0;
    alphaH[E_TOT + e] = p1;
    alphaH[2 * E_TOT + e] = p2;
    alphaH[3 * E_TOT + e] = p3;
    s0 += p0; s1 += p1; s2 += p2; s3 += p3;
  }
#pragma unroll
  for (int off = 32; off > 0; off >>= 1) {
    s0 += __shfl_xor(s0, off, 64);
    s1 += __shfl_xor(s1, off, 64);
    s2 += __shfl_xor(s2, off, 64);
    s3 += __shfl_xor(s3, off, 64);
  }
  if (lane == 0) {
    float4 r;
    r.x = 1.f / (s0 + 1e-16f);
    r.y = 1.f / (s1 + 1e-16f);
    r.z = 1.f / (s2 + 1e-16f);
    r.w = 1.f / (s3 + 1e-16f);
    inv4[n] = r;
  }
}

// ===== merged: layer-1 GEMM (25000x512x256) | layer-1 alpha+denom =====
#define G1_BLK 784   // 4 col-blocks x 196 row-blocks
__global__ __launch_bounds__(256) void gemm1_alpha_k(
    const unsigned short* __restrict__ xb, const unsigned short* __restrict__ Wt1,
    unsigned short* __restrict__ h1b,
    const float* __restrict__ es1, const float* __restrict__ ed1,
    const int* __restrict__ rs, const int* __restrict__ csr,
    float* __restrict__ alphaH, float4* __restrict__ inv4) {
  __shared__ __attribute__((aligned(16))) unsigned short As[128 * 32];
  __shared__ __attribute__((aligned(16))) unsigned short Bs[128 * 32];
  int b = blockIdx.x;
  if (b < G1_BLK) {
    gemm_body<128>(As, Bs, xb, Wt1, h1b, N_NODES, HC1, IN_CH, b & 3, b >> 2);
  } else {
    alpha_body(b - G1_BLK, es1, ed1, rs, csr, alphaH, inv4);
  }
}

// ===== merged: layer-2 GEMM (25000x64x512) | layer-2 es/ed GEMV =====
#define G2_BLK 196
__global__ __launch_bounds__(256) void gemm2_es2_k(
    const unsigned short* __restrict__ out1b, const unsigned short* __restrict__ Wt2,
    unsigned short* __restrict__ h2b,
    const float* __restrict__ wb2, float* __restrict__ es2, float* __restrict__ ed2) {
  __shared__ __attribute__((aligned(16))) unsigned short As[128 * 32];
  __shared__ __attribute__((aligned(16))) unsigned short Bs[64 * 32];
  int b = blockIdx.x;
  if (b < G2_BLK) {
    gemm_body<64>(As, Bs, out1b, Wt2, h2b, N_NODES, OUT_CH, HC1, 0, b);
  } else {
    es_body<HC1, 1, true>(b - G2_BLK, out1b, wb2, es2, ed2);
  }
}

// ===== layer-1 gather: channel-sliced + group-per-node + shfl MLP-16 =====
// saddr form: uniform hfeat base + 32-bit voffset (s<<9)+c0 (shorts, max 12.8M).
// Outer loop batches 16 edges (two coalesced (csr,alpha) fetches) -> up to 16
// independent feature loads in flight per group. VGPR ~55 < 64 cliff.
__global__ __launch_bounds__(256) void gat_agg1_g8(
    const unsigned short* __restrict__ hfeat,
    const float* __restrict__ alphaH,
    const int* __restrict__ rs, const int* __restrict__ csr,
    const float4* __restrict__ inv4, const float* __restrict__ bias,
    unsigned short* __restrict__ out) {
  int b = blockIdx.x;
  int g = b & 7;                        // channel slice 0..7
  int lane = threadIdx.x & 63, wid = threadIdx.x >> 6;
  int grp = lane >> 3, cl = lane & 7;
  int n = (b >> 3) * 32 + wid * 8 + grp;
  bool valid = n < N_NODES;
  int nn = valid ? n : N_NODES - 1;
  int h = g >> 1;
  unsigned c0 = (unsigned)(g * 64 + cl * 8);
  int beg = rs[nn], end = rs[nn + 1];
  const float* aH = alphaH + (size_t)h * E_TOT;
  int gbase = grp * 8;

  float acc[8] = {};
  for (int i = beg; i < end; i += 16) {
    int idx0 = i + cl, idx1 = i + 8 + cl;
    int sv0 = csr[idx0 < end ? idx0 : end - 1];
    float av0 = (idx0 < end) ? aH[idx0] : 0.f;
    int sv1 = csr[idx1 < end ? idx1 : end - 1];
    float av1 = (idx1 < end) ? aH[idx1] : 0.f;
#pragma unroll
    for (int e = 0; e < 8; e++) {
      unsigned sA = (unsigned)__shfl(sv0, gbase + e, 64);
      float pA = __shfl(av0, gbase + e, 64);
      unsigned sB = (unsigned)__shfl(sv1, gbase + e, 64);
      float pB = __shfl(av1, gbase + e, 64);
      bf16x8 hA = *(const bf16x8*)(hfeat + ((sA << 9) + c0));
      bf16x8 hB = *(const bf16x8*)(hfeat + ((sB << 9) + c0));
#pragma unroll
      for (int j = 0; j < 8; j++) {
        acc[j] = fmaf(bf2f((unsigned short)hA[j]), pA, acc[j]);
        acc[j] = fmaf(bf2f((unsigned short)hB[j]), pB, acc[j]);
      }
    }
  }
  if (valid) {
    float inv = ((const float*)&inv4[nn])[h];
    bf16x8 o;
#pragma unroll
    for (int j = 0; j < 8; j++) {
      float v = acc[j] * inv + bias[c0 + j];
      v = v > 0.f ? v : expm1f(v);  // ELU
      o[j] = (short)f2bf(v);
    }
    *(bf16x8*)(out + (size_t)n * 512 + c0) = o;
  }
}

// ===== layer-2 gather: group-per-node, inline softmax, saddr addressing =====
__global__ __launch_bounds__(256) void gat_agg2_g8(
    const unsigned short* __restrict__ hfeat,
    const float* __restrict__ es, const float* __restrict__ ed,
    const int* __restrict__ rs, const int* __restrict__ csr,
    const float* __restrict__ bias, float* __restrict__ out) {
  int lane = threadIdx.x & 63, wid = threadIdx.x >> 6;
  int grp = lane >> 3, cl = lane & 7;
  int n = blockIdx.x * 32 + wid * 8 + grp;
  bool valid = n < N_NODES;
  int nn = valid ? n : N_NODES - 1;
  unsigned c0 = (unsigned)(cl * 8);
  int beg = rs[nn], end = rs[nn + 1];
  int gbase = grp * 8;
  float edn = ed[nn];

  // pass 1: denominator
  float sum = 0.f;
  for (int i = beg + cl; i < end; i += 8) {
    int s = csr[i];
    sum += __expf(lrelu(es[s] + edn));
  }
#pragma unroll
  for (int off = 1; off < 8; off <<= 1) sum += __shfl_xor(sum, off, 64);
  float inv = 1.f / (sum + 1e-16f);

  // pass 2: gather with inline p
  float acc[8] = {};
  for (int i = beg; i < end; i += 8) {
    int idx = i + cl;
    bool inb = idx < end;
    int sv = csr[inb ? idx : end - 1];
    float av = inb ? __expf(lrelu(es[sv] + edn)) : 0.f;
#pragma unroll
    for (int e = 0; e < 8; e++) {
      unsigned s = (unsigned)__shfl(sv, gbase + e, 64);
      float p = __shfl(av, gbase + e, 64);
      bf16x8 hv = *(const bf16x8*)(hfeat + ((s << 6) + c0));
#pragma unroll
      for (int j = 0; j < 8; j++) acc[j] = fmaf(bf2f((unsigned short)hv[j]), p, acc[j]);
    }
  }
  if (valid) {
    float4 o0, o1;
    o0.x = acc[0] * inv + bias[c0];
    o0.y = acc[1] * inv + bias[c0 + 1];
    o0.z = acc[2] * inv + bias[c0 + 2];
    o0.w = acc[3] * inv + bias[c0 + 3];
    o1.x = acc[4] * inv + bias[c0 + 4];
    o1.y = acc[5] * inv + bias[c0 + 5];
    o1.z = acc[6] * inv + bias[c0 + 6];
    o1.w = acc[7] * inv + bias[c0 + 7];
    *(float4*)(out + (size_t)n * 64 + c0) = o0;
    *(float4*)(out + (size_t)n * 64 + c0 + 4) = o1;
  }
}

extern "C" void kernel_launch(void* const* d_in, const int* in_sizes, int n_in,
                              void* d_out, int out_size, void* d_ws, size_t ws_size,
                              hipStream_t stream) {
  const float* x   = (const float*)d_in[0];
  const int*   ei  = (const int*)d_in[1];
  const float* W1  = (const float*)d_in[2];
  const float* as1 = (const float*)d_in[3];
  const float* ad1 = (const float*)d_in[4];
  const float* b1  = (const float*)d_in[5];
  const float* W2  = (const float*)d_in[6];
  const float* as2 = (const float*)d_in[7];
  const float* ad2 = (const float*)d_in[8];
  const float* b2  = (const float*)d_in[9];
  float* out = (float*)d_out;

  const int* srcs = ei;
  const int* dsts = ei + N_EDGES;

  char* ws = (char*)d_ws;
  auto alloc = [&](size_t bytes) -> char* {
    char* p = ws;
    ws += (bytes + 255) & ~(size_t)255;
    return p;
  };
  unsigned short* xb    = (unsigned short*)alloc((size_t)N_NODES * IN_CH * 2);
  unsigned short* Wt1   = (unsigned short*)alloc((size_t)IN_CH * HC1 * 2);
  unsigned short* Wt2   = (unsigned short*)alloc((size_t)HC1 * OUT_CH * 2);
  unsigned short* h1b   = (unsigned short*)alloc((size_t)N_NODES * HC1 * 2);
  unsigned short* out1b = (unsigned short*)alloc((size_t)N_NODES * HC1 * 2);
  unsigned short* h2b   = (unsigned short*)alloc((size_t)N_NODES * OUT_CH * 2);
  float* wb1    = (float*)alloc((size_t)IN_CH * 2 * HEADS * 4);
  float* wb2    = (float*)alloc((size_t)HC1 * 2 * 4);
  float* es1    = (float*)alloc((size_t)N_NODES * HEADS * 4);
  float* ed1    = (float*)alloc((size_t)N_NODES * HEADS * 4);
  float* es2    = (float*)alloc((size_t)N_NODES * 4);
  float* ed2    = (float*)alloc((size_t)N_NODES * 4);
  float* inv4   = (float*)alloc((size_t)N_NODES * 4 * 4);
  float* alphaH = (float*)alloc((size_t)4 * E_TOT * 4);
  int*   cnt    = (int*)alloc((size_t)N_NODES * 4);
  int*   rs     = (int*)alloc((size_t)(N_NODES + 1) * 4);
  int*   cursor = (int*)alloc((size_t)N_NODES * 4);
  int*   csrS   = (int*)alloc((size_t)E_TOT * 4);

  hipMemsetAsync(cnt, 0, (size_t)N_NODES * 4, stream);

  const int gn4 = cdiv(N_NODES, 4);    // 6250
  const int gn32 = cdiv(N_NODES, 32);  // 782

  // phase A: hist + casts + transposes + folds
  prep_k<<<B_HIST + B_CAST + B_WT1 + B_WT2 + B_F1 + B_F2, 256, 0, stream>>>(
      dsts, cnt, x, xb, W1, Wt1, W2, Wt2, as1, ad1, wb1, as2, ad2, wb2);
  // phase B: scan
  scan_k<<<1, SCAN_T, 0, stream>>>(cnt, rs, cursor);
  // phase C: CSR fill | es1/ed1 GEMV  (low-VGPR, no-LDS blocks only)
  fill_es1_k<<<GE_BLK + gn4, 256, 0, stream>>>(
      srcs, dsts, rs, cursor, csrS, xb, wb1, es1, ed1);
  // phase D: gemm1 | alpha+denom
  gemm1_alpha_k<<<G1_BLK + gn4, 256, 0, stream>>>(
      xb, Wt1, h1b, es1, ed1, rs, csrS, alphaH, (float4*)inv4);
  // phase E: layer-1 aggregate
  gat_agg1_g8<<<gn32 * 8, 256, 0, stream>>>(
      h1b, alphaH, rs, csrS, (const float4*)inv4, b1, out1b);
  // phase F: gemm2 | es2/ed2 GEMV
  gemm2_es2_k<<<G2_BLK + gn4, 256, 0, stream>>>(
      out1b, Wt2, h2b, wb2, es2, ed2);
  // phase G: layer-2 aggregate (inline softmax)
  gat_agg2_g8<<<gn32, 256, 0, stream>>>(h2b, es2, ed2, rs, csrS, b2, out);
}